// Round 1
// baseline (26391.803 us; speedup 1.0000x reference)
//
#include <hip/hip_runtime.h>
#include <math.h>

#define DEV __device__ __forceinline__

constexpr int B = 8, T = 128, V = 32000, A = 64, D = 256, NS = 16, S = 128, H = 4, HD = 64;
constexpr int D2 = 2 * D;  // 512

DEV float sigm(float x) { return 1.0f / (1.0f + expf(-x)); }
DEV float geluf(float x) { return 0.5f * x * (1.0f + erff(x * 0.7071067811865476f)); }

// block-wide (256 threads) sum reduction
DEV float blk_sum256(float v, float* red) {
  #pragma unroll
  for (int o = 32; o > 0; o >>= 1) v += __shfl_down(v, o, 64);
  int lane = threadIdx.x & 63, wid = threadIdx.x >> 6;
  __syncthreads();  // protect red[] reuse across calls
  if (lane == 0) red[wid] = v;
  __syncthreads();
  return red[0] + red[1] + red[2] + red[3];
}

// ---------------- one-time setup kernels ----------------

__global__ __launch_bounds__(256) void k_setup(const float* __restrict__ aimp,
                                               const float* __restrict__ cmix,
                                               const float* __restrict__ bind,
                                               float* __restrict__ iw, float* __restrict__ cwv,
                                               float* __restrict__ sigbind) {
  int tid = threadIdx.x;
  if (tid < 64) {  // wave 0: softmax over aimp[64]
    float v = aimp[tid];
    float m = v;
    #pragma unroll
    for (int o = 32; o > 0; o >>= 1) m = fmaxf(m, __shfl_xor(m, o, 64));
    float e = expf(v - m);
    float s = e;
    #pragma unroll
    for (int o = 32; o > 0; o >>= 1) s += __shfl_xor(s, o, 64);
    iw[tid] = e / s;
  }
  if (tid == 0) {
    float a = cmix[0], b = cmix[1], m = fmaxf(a, b);
    float ea = expf(a - m), eb = expf(b - m);
    cwv[0] = ea / (ea + eb);
    cwv[1] = eb / (ea + eb);
  }
  for (int i = tid; i < NS * D; i += 256) sigbind[i] = sigm(bind[i]);
}

__global__ __launch_bounds__(256) void k_percepts(const int* __restrict__ idx,
                                                  const float* __restrict__ emb,
                                                  const float* __restrict__ pos,
                                                  float* __restrict__ P) {
  int i = blockIdx.x * 256 + threadIdx.x;  // over B*T*D
  if (i < B * T * D) {
    int d = i & (D - 1);
    int bt = i / D;
    int t = bt & (T - 1);
    P[i] = emb[(size_t)idx[bt] * D + d] + pos[t * D + d];
  }
}

// cvec[j] = sum_v ba2[v]*Wfb[v,j] + bfb[j]
__global__ __launch_bounds__(256) void k_cvec(const float* __restrict__ Wfb,
                                              const float* __restrict__ ba2,
                                              const float* __restrict__ bfb,
                                              float* __restrict__ cvec) {
  int j = blockIdx.x, tid = threadIdx.x;
  float s = 0.f;
  for (int v = tid; v < V; v += 256) s += ba2[v] * Wfb[(size_t)v * D + j];
  __shared__ float red[256];
  red[tid] = s;
  __syncthreads();
  for (int o = 128; o > 0; o >>= 1) {
    if (tid < o) red[tid] += red[tid + o];
    __syncthreads();
  }
  if (tid == 0) cvec[j] = red[0] + bfb[j];
}

// M partials: M[i,j] = sum_v Wa2[i,v]*Wfb[v,j]  (split-K over 16 v-chunks of 2000)
__global__ __launch_bounds__(256) void k_mpart(const float* __restrict__ Wa2,
                                               const float* __restrict__ Wfb,
                                               float* __restrict__ part) {
  int it = blockIdx.y;  // 0..15 : 32 rows of M each
  int vc = blockIdx.x;  // 0..15 : 2000 v each
  int j = threadIdx.x;
  int i0 = it * 32, v0 = vc * 2000;
  __shared__ float a_l[32 * 125];
  float acc[32];
  #pragma unroll
  for (int r = 0; r < 32; r++) acc[r] = 0.f;
  for (int vb = 0; vb < 2000; vb += 125) {
    for (int l = threadIdx.x; l < 32 * 125; l += 256) {
      int r = l / 125, c = l - r * 125;
      a_l[l] = Wa2[(size_t)(i0 + r) * V + v0 + vb + c];
    }
    __syncthreads();
    for (int c = 0; c < 125; c++) {
      float w = Wfb[(size_t)(v0 + vb + c) * D + j];
      #pragma unroll
      for (int r = 0; r < 32; r++) acc[r] += a_l[r * 125 + c] * w;
    }
    __syncthreads();
  }
  for (int r = 0; r < 32; r++) part[((size_t)vc * D2 + i0 + r) * D + j] = acc[r];
}

__global__ __launch_bounds__(256) void k_mreduce(const float* __restrict__ part,
                                                 float* __restrict__ M) {
  int i = blockIdx.x, j = threadIdx.x;
  float s = 0.f;
  for (int vc = 0; vc < 16; vc++) s += part[((size_t)vc * D2 + i) * D + j];
  M[i * D + j] = s;
}

// t=0 bootstrap: zero agents, mod_0 = p0*(1+sigmoid([bfb,p0]@Wfg+bfg))
__global__ __launch_bounds__(256) void k_step0(const float* __restrict__ P,
                                               const float* __restrict__ bfb,
                                               const float* __restrict__ Wfg,
                                               const float* __restrict__ bfg,
                                               float* __restrict__ agents,
                                               float* __restrict__ mod) {
  int b = blockIdx.x, tid = threadIdx.x;
  for (int i = b * (A * D) + tid; i < (b + 1) * (A * D); i += 256) agents[i] = 0.f;
  __shared__ float cat[512];
  cat[tid] = bfb[tid];
  cat[256 + tid] = P[(b * T + 0) * D + tid];
  __syncthreads();
  float acc = bfg[tid];
  for (int k = 0; k < 512; k++) acc += cat[k] * Wfg[k * D + tid];
  float fg = sigm(acc);
  float pt = cat[256 + tid];
  mod[b * D + tid] = pt * (1.f + fg);
}

// ---------------- per-step kernels ----------------

// sens + agents[:, :NS] += sens ; inter[c] = anet[c] @ agents
__global__ __launch_bounds__(256) void k_stepB(const float* __restrict__ Wsens,
                                               const float* __restrict__ bsens,
                                               const float* __restrict__ sigbind,
                                               const float* __restrict__ anet,
                                               const float* __restrict__ mod,
                                               float* __restrict__ agents,
                                               float* __restrict__ inter) {
  int b = blockIdx.y;   // 0..7
  int dc = blockIdx.x;  // 0..7 (chunk of 32 d)
  int d0 = dc * 32;
  int tid = threadIdx.x;
  __shared__ float mod_l[256];
  __shared__ float ag_l[64][33];
  __shared__ float an_l[2 * 64 * 64];
  mod_l[tid] = mod[b * D + tid];
  for (int l = tid; l < 2 * 64 * 64; l += 256) an_l[l] = anet[l];
  for (int l = tid; l < 64 * 32; l += 256) {
    int j = l >> 5, dl = l & 31;
    ag_l[j][dl] = agents[(b * A + j) * D + d0 + dl];
  }
  __syncthreads();
  // sens for j<NS
  for (int l = tid; l < NS * 32; l += 256) {
    int j = l >> 5, dl = l & 31;
    int col = j * D + d0 + dl;
    float acc = bsens[col];
    for (int k = 0; k < D; k++) acc += mod_l[k] * Wsens[k * (NS * D) + col];
    float nv = ag_l[j][dl] + acc * sigbind[col];
    ag_l[j][dl] = nv;
    agents[(b * A + j) * D + d0 + dl] = nv;
  }
  __syncthreads();
  // inter
  for (int l = tid; l < 2 * 64 * 32; l += 256) {
    int c = l >> 11;
    int rem = l & 2047;
    int i = rem >> 5, dl = rem & 31;
    const float* an = &an_l[(c * 64 + i) * 64];
    float acc = 0.f;
    #pragma unroll 8
    for (int j = 0; j < 64; j++) acc += an[j] * ag_l[j][dl];
    inter[(((c * B) + b) * A + i) * D + d0 + dl] = acc;
  }
}

// per-row cand/gate/LN combine for both channels -> new agents
__global__ __launch_bounds__(256) void k_stepC(const float* __restrict__ Wc,
                                               const float* __restrict__ bc,
                                               const float* __restrict__ Wg,
                                               const float* __restrict__ bg,
                                               const float* __restrict__ lng,
                                               const float* __restrict__ lnb,
                                               const float* __restrict__ cwv,
                                               const float* __restrict__ inter,
                                               float* __restrict__ agents) {
  int r0 = blockIdx.x * 4;  // 4 rows (b*A+a) per block
  int tid = threadIdx.x;
  __shared__ float ag_l[4][256];
  __shared__ float in_l[4][2][256];
  __shared__ float red[4];
  for (int rr = 0; rr < 4; rr++) {
    ag_l[rr][tid] = agents[(r0 + rr) * D + tid];
    in_l[rr][0][tid] = inter[(r0 + rr) * D + tid];
    in_l[rr][1][tid] = inter[B * A * D + (r0 + rr) * D + tid];
  }
  __syncthreads();
  float c0[4] = {0, 0, 0, 0}, c1[4] = {0, 0, 0, 0};
  float g0[4] = {0, 0, 0, 0}, g1[4] = {0, 0, 0, 0};
  for (int k = 0; k < 256; k++) {
    float wc0 = Wc[k * D + tid];
    float wc1 = Wc[D * D + k * D + tid];
    float wg0 = Wg[k * D + tid];
    float wg1 = Wg[D2 * D + k * D + tid];
    #pragma unroll
    for (int rr = 0; rr < 4; rr++) {
      c0[rr] += in_l[rr][0][k] * wc0;
      c1[rr] += in_l[rr][1][k] * wc1;
      g0[rr] += ag_l[rr][k] * wg0;
      g1[rr] += ag_l[rr][k] * wg1;
    }
  }
  for (int k = 0; k < 256; k++) {
    float wg0 = Wg[(256 + k) * D + tid];
    float wg1 = Wg[D2 * D + (256 + k) * D + tid];
    #pragma unroll
    for (int rr = 0; rr < 4; rr++) {
      g0[rr] += in_l[rr][0][k] * wg0;
      g1[rr] += in_l[rr][1][k] * wg1;
    }
  }
  float cw0 = cwv[0], cw1 = cwv[1];
  float bc0 = bc[tid], bc1 = bc[D + tid];
  float bg0 = bg[tid], bg1 = bg[D + tid];
  float lg0 = lng[tid], lg1 = lng[D + tid];
  float lb0 = lnb[tid], lb1 = lnb[D + tid];
  for (int rr = 0; rr < 4; rr++) {
    float cand0 = geluf(c0[rr] + bc0);
    float cand1 = geluf(c1[rr] + bc1);
    float gate0 = sigm(g0[rr] + bg0);
    float gate1 = sigm(g1[rr] + bg1);
    float a = ag_l[rr][tid];
    float v0 = gate0 * cand0 + (1.f - gate0) * a;
    float v1 = gate1 * cand1 + (1.f - gate1) * a;
    float s0 = blk_sum256(v0, red);
    float q0 = blk_sum256(v0 * v0, red);
    float s1 = blk_sum256(v1, red);
    float q1 = blk_sum256(v1 * v1, red);
    float m0 = s0 * (1.f / 256.f), var0 = q0 * (1.f / 256.f) - m0 * m0;
    float m1 = s1 * (1.f / 256.f), var1 = q1 * (1.f / 256.f) - m1 * m1;
    float ln0 = (v0 - m0) * rsqrtf(var0 + 1e-5f) * lg0 + lb0;
    float ln1 = (v1 - m1) * rsqrtf(var1 + 1e-5f) * lg1 + lb1;
    agents[(r0 + rr) * D + tid] = cw0 * ln0 + cw1 * ln1;
  }
}

// consensus + memory attention + K/V cache + h + next-step mod. One block per b.
__global__ __launch_bounds__(256) void k_stepD(
    int t, const float* __restrict__ P, const float* __restrict__ iw,
    const float* __restrict__ Wq, const float* __restrict__ bq,
    const float* __restrict__ Wk, const float* __restrict__ bk,
    const float* __restrict__ Wv, const float* __restrict__ bv,
    const float* __restrict__ Wo, const float* __restrict__ bo,
    const float* __restrict__ Wmg, const float* __restrict__ bmg,
    const float* __restrict__ mlng, const float* __restrict__ mlnb,
    const float* __restrict__ Wa1, const float* __restrict__ ba1,
    const float* __restrict__ M, const float* __restrict__ cvec,
    const float* __restrict__ Wfg, const float* __restrict__ bfg,
    const float* __restrict__ agents, float* __restrict__ Kc, float* __restrict__ Vc,
    float* __restrict__ Hall, float* __restrict__ mod) {
  int b = blockIdx.x, tid = threadIdx.x;
  __shared__ float cons_l[256], q_l[256], o_l[256], cf_l[256], h_l[512];
  __shared__ float sc_l[4][128];
  __shared__ float den_l[4];
  __shared__ float red[4];
  // cons = sum_a iw[a]*agents[b,a,:]
  float acc = 0.f;
  for (int a = 0; a < A; a++) acc += iw[a] * agents[(b * A + a) * D + tid];
  cons_l[tid] = acc;
  __syncthreads();
  float consd = acc;
  float cfd;
  if (t > 0) {
    float q = bq[tid];
    for (int k = 0; k < 256; k++) q += cons_l[k] * Wq[k * D + tid];
    q_l[tid] = q;
    __syncthreads();
    // scores
    for (int p = tid; p < 4 * 128; p += 256) {
      int h = p >> 7, s = p & 127;
      if (s < t) {
        const float* krow = &Kc[(b * S + s) * D + h * HD];
        const float* qh = &q_l[h * HD];
        float sc = 0.f;
        #pragma unroll 8
        for (int e = 0; e < HD; e++) sc += qh[e] * krow[e];
        sc_l[h][s] = sc * 0.125f;
      }
    }
    __syncthreads();
    // softmax per head (wave w -> head w)
    int h = tid >> 6, lane = tid & 63;
    {
      float m = -1e30f;
      for (int s = lane; s < t; s += 64) m = fmaxf(m, sc_l[h][s]);
      #pragma unroll
      for (int o = 32; o > 0; o >>= 1) m = fmaxf(m, __shfl_xor(m, o, 64));
      float sum = 0.f;
      for (int s = lane; s < t; s += 64) {
        float e = expf(sc_l[h][s] - m);
        sc_l[h][s] = e;
        sum += e;
      }
      #pragma unroll
      for (int o = 32; o > 0; o >>= 1) sum += __shfl_xor(sum, o, 64);
      if (lane == 0) den_l[h] = sum;
    }
    __syncthreads();
    // rec (pre-Wo), thread d=tid, head = tid>>6
    float r = 0.f;
    for (int s = 0; s < t; s++) r += sc_l[h][s] * Vc[(b * S + s) * D + tid];
    r /= den_l[h];
    __syncthreads();
    q_l[tid] = r;  // reuse as rec storage
    __syncthreads();
    float o = bo[tid];
    for (int k = 0; k < 256; k++) o += q_l[k] * Wo[k * D + tid];
    o_l[tid] = o;
    __syncthreads();
    float mg = bmg[tid];
    for (int k = 0; k < 256; k++) mg += cons_l[k] * Wmg[k * D + tid];
    for (int k = 0; k < 256; k++) mg += o_l[k] * Wmg[(256 + k) * D + tid];
    mg = sigm(mg);
    float val = consd + mg * o;
    float s1 = blk_sum256(val, red);
    float s2 = blk_sum256(val * val, red);
    float mean = s1 * (1.f / 256.f), var = s2 * (1.f / 256.f) - mean * mean;
    cfd = (val - mean) * rsqrtf(var + 1e-5f) * mlng[tid] + mlnb[tid];
  } else {
    cfd = consd;
  }
  __syncthreads();
  cf_l[tid] = cfd;
  __syncthreads();
  // K/V cache for slot t
  float kk = bk[tid], vv = bv[tid];
  for (int k = 0; k < 256; k++) {
    float c = cf_l[k];
    kk += c * Wk[k * D + tid];
    vv += c * Wv[k * D + tid];
  }
  Kc[(b * S + t) * D + tid] = kk;
  Vc[(b * S + t) * D + tid] = vv;
  // h = gelu(cons @ Wa1 + ba1)   [512]
  for (int m = tid; m < 512; m += 256) {
    float hh = ba1[m];
    for (int k = 0; k < 256; k++) hh += cf_l[k] * Wa1[k * D2 + m];
    hh = geluf(hh);
    h_l[m] = hh;
    Hall[((size_t)b * T + t) * D2 + m] = hh;
  }
  __syncthreads();
  if (t < T - 1) {
    // fb = h @ M + cvec
    float fb = cvec[tid];
    for (int k = 0; k < 512; k++) fb += h_l[k] * M[k * D + tid];
    float ptn = P[(b * T + t + 1) * D + tid];
    q_l[tid] = fb;
    o_l[tid] = ptn;
    __syncthreads();
    float fg = bfg[tid];
    for (int k = 0; k < 256; k++) fg += q_l[k] * Wfg[k * D + tid];
    for (int k = 0; k < 256; k++) fg += o_l[k] * Wfg[(256 + k) * D + tid];
    fg = sigm(fg);
    mod[b * D + tid] = ptn * (1.f + fg);
  }
}

// final: out[bt, v] = Hall[bt,:] @ Wa2 + ba2   (h values read via uniform/scalar loads)
__global__ __launch_bounds__(256) void k_logits(const float* __restrict__ Hall,
                                                const float* __restrict__ Wa2,
                                                const float* __restrict__ ba2,
                                                float* __restrict__ out) {
  int rt = blockIdx.y;                      // 0..31 (row tiles of 32)
  int v = blockIdx.x * 256 + threadIdx.x;   // 0..31999
  const float* hrow = Hall + (size_t)rt * 32 * D2;
  float acc[32];
  float bb = ba2[v];
  #pragma unroll
  for (int r = 0; r < 32; r++) acc[r] = bb;
  for (int k = 0; k < D2; k++) {
    float w = Wa2[(size_t)k * V + v];
    #pragma unroll
    for (int r = 0; r < 32; r++) acc[r] += hrow[r * D2 + k] * w;
  }
  for (int r = 0; r < 32; r++) out[(size_t)(rt * 32 + r) * V + v] = acc[r];
}

// ---------------- launcher ----------------

extern "C" void kernel_launch(void* const* d_in, const int* in_sizes, int n_in,
                              void* d_out, int out_size, void* d_ws, size_t ws_size,
                              hipStream_t stream) {
  const int* idx = (const int*)d_in[0];
  const float* emb = (const float*)d_in[1];
  const float* pos = (const float*)d_in[2];
  const float* Wsens = (const float*)d_in[3];
  const float* bsens = (const float*)d_in[4];
  const float* Wfb = (const float*)d_in[5];
  const float* bfb = (const float*)d_in[6];
  const float* Wfg = (const float*)d_in[7];
  const float* bfg = (const float*)d_in[8];
  const float* bind = (const float*)d_in[9];
  const float* anet = (const float*)d_in[10];
  const float* Wg = (const float*)d_in[11];
  const float* bg = (const float*)d_in[12];
  const float* Wc = (const float*)d_in[13];
  const float* bc = (const float*)d_in[14];
  const float* lng = (const float*)d_in[15];
  const float* lnb = (const float*)d_in[16];
  const float* cmix = (const float*)d_in[17];
  const float* aimp = (const float*)d_in[18];
  const float* Wq = (const float*)d_in[19];
  const float* bq = (const float*)d_in[20];
  const float* Wk = (const float*)d_in[21];
  const float* bk = (const float*)d_in[22];
  const float* Wv = (const float*)d_in[23];
  const float* bv = (const float*)d_in[24];
  const float* Wo = (const float*)d_in[25];
  const float* bo = (const float*)d_in[26];
  const float* Wmg = (const float*)d_in[27];
  const float* bmg = (const float*)d_in[28];
  const float* mlng = (const float*)d_in[29];
  const float* mlnb = (const float*)d_in[30];
  const float* Wa1 = (const float*)d_in[31];
  const float* ba1 = (const float*)d_in[32];
  const float* Wa2 = (const float*)d_in[33];
  const float* ba2 = (const float*)d_in[34];

  float* ws = (float*)d_ws;
  // workspace layout (floats)
  float* M = ws;                 // 512*256      = 131072
  float* cvec = ws + 131072;     // 256
  float* iw = ws + 131328;       // 64
  float* cw = ws + 131392;       // 2 (+pad)
  float* sigbind = ws + 131456;  // 4096
  float* P = ws + 135552;        // B*T*D       = 262144
  float* agents = ws + 397696;   // B*A*D       = 131072
  float* inter = ws + 528768;    // 2*B*A*D     = 262144
  float* mod = ws + 790912;      // B*D         = 2048
  float* Kc = ws + 792960;       // B*S*D       = 262144
  float* Vc = ws + 1055104;      // B*S*D       = 262144
  float* Hall = ws + 1317248;    // B*T*2D      = 524288
  float* Mpart = ws + 1841536;   // 16*512*256  = 2097152   (end 3938688 floats ~ 15.8 MB)

  k_setup<<<1, 256, 0, stream>>>(aimp, cmix, bind, iw, cw, sigbind);
  k_percepts<<<dim3((B * T * D + 255) / 256), 256, 0, stream>>>(idx, emb, pos, P);
  k_cvec<<<256, 256, 0, stream>>>(Wfb, ba2, bfb, cvec);
  k_mpart<<<dim3(16, 16), 256, 0, stream>>>(Wa2, Wfb, Mpart);
  k_mreduce<<<512, 256, 0, stream>>>(Mpart, M);
  k_step0<<<B, 256, 0, stream>>>(P, bfb, Wfg, bfg, agents, mod);

  for (int t = 0; t < T; t++) {
    k_stepB<<<dim3(8, B), 256, 0, stream>>>(Wsens, bsens, sigbind, anet, mod, agents, inter);
    k_stepC<<<128, 256, 0, stream>>>(Wc, bc, Wg, bg, lng, lnb, cw, inter, agents);
    k_stepD<<<B, 256, 0, stream>>>(t, P, iw, Wq, bq, Wk, bk, Wv, bv, Wo, bo, Wmg, bmg,
                                   mlng, mlnb, Wa1, ba1, M, cvec, Wfg, bfg, agents, Kc, Vc,
                                   Hall, mod);
  }
  k_logits<<<dim3(125, 32), 256, 0, stream>>>(Hall, Wa2, ba2, (float*)d_out);
}